// Round 1
// 1157.582 us; speedup vs baseline: 1.0652x; 1.0652x over previous
//
#include <hip/hip_runtime.h>
#include <hip/hip_bf16.h>

// Problem constants
#define BB 8
#define SS 1024
#define DD 1024
#define HH 16
#define DKK 64
#define MM (BB*SS)          // 8192
#define OUT_ELEMS ((size_t)BB*SS*DD)          // 8388608
#define ATTN_ELEMS ((size_t)BB*HH*SS*SS)      // 134217728

using short8 = __attribute__((ext_vector_type(8))) short;
using f32x4  = __attribute__((ext_vector_type(4))) float;

__device__ __forceinline__ ushort f2b(float f) {
    unsigned u = __float_as_uint(f);
    u = u + 0x7fffu + ((u >> 16) & 1u);
    return (ushort)(u >> 16);
}

// ---------------------------------------------------------------------------
// Weight transpose + bf16 convert: Wt[n][k] = bf16(W[k][n]), 1024x1024 each.
// ---------------------------------------------------------------------------
__global__ __launch_bounds__(256) void transpose_w(
    const float* __restrict__ w0, const float* __restrict__ w1,
    const float* __restrict__ w2, const float* __restrict__ w3,
    ushort* __restrict__ t0, ushort* __restrict__ t1,
    ushort* __restrict__ t2, ushort* __restrict__ t3)
{
    const float* W; ushort* T;
    switch (blockIdx.z) {
        case 0: W = w0; T = t0; break;
        case 1: W = w1; T = t1; break;
        case 2: W = w2; T = t2; break;
        default: W = w3; T = t3; break;
    }
    __shared__ float tile[64 * 65];
    const int k0 = blockIdx.x * 64, n0 = blockIdx.y * 64;
    const int t = threadIdx.x;
#pragma unroll
    for (int i = 0; i < 16; i++) {
        int idx = i * 256 + t;
        int r = idx >> 6, c = idx & 63;
        tile[r * 65 + c] = W[(size_t)(k0 + r) * DD + n0 + c];
    }
    __syncthreads();
#pragma unroll
    for (int i = 0; i < 16; i++) {
        int idx = i * 256 + t;
        int nr = idx >> 6, kc = idx & 63;
        T[(size_t)(n0 + nr) * DD + k0 + kc] = f2b(tile[kc * 65 + nr]);
    }
}

// ---------------------------------------------------------------------------
// GEMM: C[M=8192][N=1024] = A[f32, MxK row-major] * Wt^T  (Wt is [N][K] bf16)
// 128x128 tile, 4 waves, each wave 64x64 via 4x4 frags of 16x16x32 MFMA.
// A staged to LDS with f32->bf16 convert; B-frags read directly from Wt (L2).
// Grid is 1-D (512 blocks) with chunked XCD swizzle: default round-robin puts
// the 8 n-blocks sharing one A m-panel on 8 DIFFERENT XCDs (zero L2 sharing).
// Swizzle gives each XCD 8 complete m-panels -> A panel fetched once per XCD.
// MODE 0: bf16 out, head-major [B,H,S,64]
// MODE 1: bf16 out, V-transposed [B,H,64,S]
// MODE 2: f32 out, row-major [M][N]
// ---------------------------------------------------------------------------
template <int MODE>
__global__ __launch_bounds__(256) void gemm_bt(
    const float* __restrict__ A, const ushort* __restrict__ Bt,
    void* __restrict__ Cout)
{
    constexpr int K = 1024;
    const int t = threadIdx.x;
    // chunked bijective XCD swizzle (nwg=512, 512%8==0): XCD k = wg%8 gets
    // linear ids [k*64, (k+1)*64) -> m-panels [k*8, k*8+8), all 8 n-blocks.
    const int wg = blockIdx.x;
    const int l  = (wg & 7) * 64 + (wg >> 3);
    const int n0 = (l & 7) * 128, m0 = (l >> 3) * 128;
    const int lane = t & 63, w = t >> 6;
    const int li = lane & 15, quad = lane >> 4;
    const int wm = w >> 1, wn = w & 1;

    __shared__ ushort As[128 * 40];   // row stride 40 elems = 80 B (16B aligned)

    f32x4 acc[4][4];
    const f32x4 zf = {0.f, 0.f, 0.f, 0.f};
#pragma unroll
    for (int mf = 0; mf < 4; mf++)
#pragma unroll
        for (int nf = 0; nf < 4; nf++) acc[mf][nf] = zf;

    for (int kk = 0; kk < K; kk += 32) {
        __syncthreads();
#pragma unroll
        for (int i = 0; i < 4; i++) {
            int row = (t >> 3) + i * 32;
            float4 a4 = *(const float4*)&A[(size_t)(m0 + row) * K + kk + (t & 7) * 4];
            ushort4 u4 = make_ushort4(f2b(a4.x), f2b(a4.y), f2b(a4.z), f2b(a4.w));
            *(ushort4*)&As[row * 40 + (t & 7) * 4] = u4;
        }
        __syncthreads();

        short8 af[4], bf[4];
#pragma unroll
        for (int mf = 0; mf < 4; mf++)
            af[mf] = *(const short8*)&As[(wm * 64 + mf * 16 + li) * 40 + quad * 8];
#pragma unroll
        for (int nf = 0; nf < 4; nf++)
            bf[nf] = *(const short8*)&Bt[(size_t)(n0 + wn * 64 + nf * 16 + li) * K + kk + quad * 8];
#pragma unroll
        for (int mf = 0; mf < 4; mf++)
#pragma unroll
            for (int nf = 0; nf < 4; nf++)
                acc[mf][nf] = __builtin_amdgcn_mfma_f32_16x16x32_bf16(af[mf], bf[nf], acc[mf][nf], 0, 0, 0);
    }

#pragma unroll
    for (int mf = 0; mf < 4; mf++)
#pragma unroll
        for (int nf = 0; nf < 4; nf++)
#pragma unroll
            for (int r = 0; r < 4; r++) {
                int m = m0 + wm * 64 + mf * 16 + quad * 4 + r;
                int n = n0 + wn * 64 + nf * 16 + li;
                float v = acc[mf][nf][r];
                if (MODE == 0) {
                    int b = m >> 10, s = m & 1023, h = n >> 6, d = n & 63;
                    ((ushort*)Cout)[((size_t)(b * HH + h) * SS + s) * 64 + d] = f2b(v);
                } else if (MODE == 1) {
                    int b = m >> 10, s = m & 1023, h = n >> 6, d = n & 63;
                    ((ushort*)Cout)[((size_t)(b * HH + h) * 64 + d) * SS + s] = f2b(v);
                } else {
                    ((float*)Cout)[(size_t)m * 1024 + n] = v;
                }
            }
}

// ---------------------------------------------------------------------------
// Pass 1 of attention: per (b,h), compute row inverse-sums and the normalized
// context. Work-balanced: each block handles the q-tile PAIR (pr, 15-pr) so
// every block does exactly 34 key-chunks (vs 2..32 before -> 26% occupancy).
// Barrier-free: the P tile is per-wave; in-wave DS ops execute in order, so a
// compiler fence replaces the two per-chunk __syncthreads().
// ---------------------------------------------------------------------------
__global__ __launch_bounds__(256) void attn_pv(
    const ushort* __restrict__ Qp, const ushort* __restrict__ Kp,
    const ushort* __restrict__ VpT, float* __restrict__ Invs,
    float* __restrict__ Ctx)
{
    const int pr = blockIdx.x;          // 0..7 (tile pair)
    const int h  = blockIdx.y;          // 0..15
    const int b  = blockIdx.z;          // 0..7
    const int bh = b * HH + h;
    const int t = threadIdx.x;
    const int w = t >> 6, lane = t & 63;
    const int li = lane & 15, quad = lane >> 4;

    const ushort* Qh = Qp  + (size_t)bh * SS * 64;
    const ushort* Kh = Kp  + (size_t)bh * SS * 64;
    const ushort* Vt = VpT + (size_t)bh * 64 * SS;

    __shared__ ushort Ps[4][16 * 32];   // per-wave P tile [16 q][32 keys]
    ushort* myP = Ps[w];
    const f32x4 zf = {0.f, 0.f, 0.f, 0.f};

    for (int sel = 0; sel < 2; sel++) {
        const int qt = sel ? (15 - pr) : pr;
        const int qbase = qt * 64 + w * 16;

        // Q fragments for this wave's 16 rows (full DK=64 as two K=32 frags)
        short8 aq0 = *(const short8*)&Qh[(size_t)(qbase + li) * 64 + quad * 8];
        short8 aq1 = *(const short8*)&Qh[(size_t)(qbase + li) * 64 + 32 + quad * 8];

        float lsum[4] = {0.f, 0.f, 0.f, 0.f};
        f32x4 cacc[4];
#pragma unroll
        for (int vf = 0; vf < 4; vf++) cacc[vf] = zf;

        const int nch = (qt + 1) * 2;   // 32-key chunks covering cols 0..qt*64+63

        for (int c = 0; c < nch; c++) {
            const int kb = c * 32;
#pragma unroll
            for (int half = 0; half < 2; half++) {
                const int col = kb + half * 16 + li;
                short8 bk0 = *(const short8*)&Kh[(size_t)col * 64 + quad * 8];
                short8 bk1 = *(const short8*)&Kh[(size_t)col * 64 + 32 + quad * 8];
                f32x4 s = __builtin_amdgcn_mfma_f32_16x16x32_bf16(aq0, bk0, zf, 0, 0, 0);
                s = __builtin_amdgcn_mfma_f32_16x16x32_bf16(aq1, bk1, s, 0, 0, 0);
#pragma unroll
                for (int r = 0; r < 4; r++) {
                    const int row = qbase + quad * 4 + r;
                    float p = (col <= row) ? __expf(s[r] * 0.125f) : 0.f;
                    lsum[r] += p;
                    myP[(quad * 4 + r) * 32 + half * 16 + li] = f2b(p);
                }
            }
            // Per-wave LDS RAW: compiler fence orders stores before the load;
            // the DS pipe is in-order within a wave, backend inserts lgkmcnt.
            asm volatile("" ::: "memory");
            short8 ap = *(const short8*)&myP[li * 32 + quad * 8];
#pragma unroll
            for (int vf = 0; vf < 4; vf++) {
                short8 bv = *(const short8*)&Vt[(size_t)(vf * 16 + li) * SS + kb + quad * 8];
                cacc[vf] = __builtin_amdgcn_mfma_f32_16x16x32_bf16(ap, bv, cacc[vf], 0, 0, 0);
            }
            asm volatile("" ::: "memory");  // P reads done before next chunk's writes
        }

        // Row-sum reduce across the 16 lanes holding each row
#pragma unroll
        for (int r = 0; r < 4; r++) {
            float v = lsum[r];
            v += __shfl_xor(v, 1, 64);
            v += __shfl_xor(v, 2, 64);
            v += __shfl_xor(v, 4, 64);
            v += __shfl_xor(v, 8, 64);
            lsum[r] = 1.f / v;
        }
        if (li == 0) {
#pragma unroll
            for (int r = 0; r < 4; r++)
                Invs[(size_t)bh * SS + qbase + quad * 4 + r] = lsum[r];
        }

        // Normalize + store context (f32, [B,S,H*64] row-major)
#pragma unroll
        for (int vf = 0; vf < 4; vf++)
#pragma unroll
            for (int r = 0; r < 4; r++) {
                const int s_idx = qbase + quad * 4 + r;
                Ctx[((size_t)b * SS + s_idx) * DD + h * 64 + vf * 16 + li] = cacc[vf][r] * lsum[r];
            }
    }
}

// ---------------------------------------------------------------------------
// Pass 2: stream out the full attn matrix (536 MB f32). Uniform grid of 4096
// blocks, each block = 64 q-rows x 512 cols of one (b,h). Fully-masked 64-col
// chunks are written as float4 zeros (256B/row segments); live chunks
// recompute scores via MFMA and scale by the precomputed inverse sums.
// Target: HBM-write-bound (~6 TB/s).
// ---------------------------------------------------------------------------
__global__ __launch_bounds__(256) void attn_write(
    const ushort* __restrict__ Qp, const ushort* __restrict__ Kp,
    const float* __restrict__ Invs, float* __restrict__ attn)
{
    const int qt = blockIdx.x >> 1;     // 0..15
    const int ch = blockIdx.x & 1;      // column half (0: cols 0..511, 1: 512..1023)
    const int h  = blockIdx.y;
    const int b  = blockIdx.z;
    const int bh = b * HH + h;
    const int t = threadIdx.x;
    const int w = t >> 6, lane = t & 63;
    const int li = lane & 15, quad = lane >> 4;
    const int qbase = qt * 64 + w * 16;
    const int c0 = ch * 512;

    const ushort* Qh = Qp + (size_t)bh * SS * 64;
    const ushort* Kh = Kp + (size_t)bh * SS * 64;
    float* arow = attn + (size_t)bh * SS * SS;

    const f32x4 zf = {0.f, 0.f, 0.f, 0.f};

    short8 aq0 = *(const short8*)&Qh[(size_t)(qbase + li) * 64 + quad * 8];
    short8 aq1 = *(const short8*)&Qh[(size_t)(qbase + li) * 64 + 32 + quad * 8];
    float inv[4];
#pragma unroll
    for (int r = 0; r < 4; r++)
        inv[r] = Invs[(size_t)bh * SS + qbase + quad * 4 + r];

    for (int c64 = 0; c64 < 8; c64++) {
        const int kb = c0 + c64 * 64;
        if (kb > qbase + 15) {
            // entire 64-col chunk masked for this wave's rows: vector zero-fill
#pragma unroll
            for (int r = 0; r < 4; r++) {
                const int row = qbase + quad * 4 + r;
                *(f32x4*)&arow[(size_t)row * SS + kb + li * 4] = zf;
            }
        } else {
#pragma unroll
            for (int q16 = 0; q16 < 4; q16++) {
                const int col = kb + q16 * 16 + li;
                short8 bk0 = *(const short8*)&Kh[(size_t)col * 64 + quad * 8];
                short8 bk1 = *(const short8*)&Kh[(size_t)col * 64 + 32 + quad * 8];
                f32x4 s = __builtin_amdgcn_mfma_f32_16x16x32_bf16(aq0, bk0, zf, 0, 0, 0);
                s = __builtin_amdgcn_mfma_f32_16x16x32_bf16(aq1, bk1, s, 0, 0, 0);
#pragma unroll
                for (int r = 0; r < 4; r++) {
                    const int row = qbase + quad * 4 + r;
                    float p = (col <= row) ? __expf(s[r] * 0.125f) * inv[r] : 0.f;
                    arow[(size_t)row * SS + col] = p;
                }
            }
        }
    }
}

// ---------------------------------------------------------------------------
// Residual add + LayerNorm (gamma=1,beta=0), in-place on pre-LN rows in d_out.
// One block per row of 1024.
// ---------------------------------------------------------------------------
__global__ __launch_bounds__(256) void ln_kernel(
    const float* __restrict__ res, float* __restrict__ io)
{
    const int row = blockIdx.x;
    const int t = threadIdx.x;
    float4 p4 = *(const float4*)&io[(size_t)row * DD + t * 4];
    float4 r4 = *(const float4*)&res[(size_t)row * DD + t * 4];
    float x0 = p4.x + r4.x, x1 = p4.y + r4.y, x2 = p4.z + r4.z, x3 = p4.w + r4.w;
    float s  = x0 + x1 + x2 + x3;
    float ss = x0 * x0 + x1 * x1 + x2 * x2 + x3 * x3;
#pragma unroll
    for (int m = 1; m < 64; m <<= 1) {
        s  += __shfl_xor(s, m, 64);
        ss += __shfl_xor(ss, m, 64);
    }
    __shared__ float red[8];
    const int w = t >> 6, lane = t & 63;
    if (lane == 0) { red[w] = s; red[4 + w] = ss; }
    __syncthreads();
    if (t == 0) {
        float S1 = red[0] + red[1] + red[2] + red[3];
        float S2 = red[4] + red[5] + red[6] + red[7];
        float mu = S1 * (1.f / 1024.f);
        float var = S2 * (1.f / 1024.f) - mu * mu;
        red[0] = mu;
        red[1] = rsqrtf(var + 1e-5f);
    }
    __syncthreads();
    float mu = red[0], rs = red[1];
    float4 o;
    o.x = (x0 - mu) * rs; o.y = (x1 - mu) * rs;
    o.z = (x2 - mu) * rs; o.w = (x3 - mu) * rs;
    *(float4*)&io[(size_t)row * DD + t * 4] = o;
}

// ---------------------------------------------------------------------------
extern "C" void kernel_launch(void* const* d_in, const int* in_sizes, int n_in,
                              void* d_out, int out_size, void* d_ws, size_t ws_size,
                              hipStream_t stream)
{
    const float* Xq  = (const float*)d_in[0];
    const float* Xk  = (const float*)d_in[1];
    const float* Xv  = (const float*)d_in[2];
    // d_in[3] = attn_mask (causal) — computed analytically, unused
    const float* Wq  = (const float*)d_in[4];
    const float* Wk  = (const float*)d_in[5];
    const float* Wv  = (const float*)d_in[6];
    const float* Wfc = (const float*)d_in[7];

    char* ws = (char*)d_ws;
    // ws layout (88 MB total):
    //   0      : Wt0..Wt3   4 x 2 MB  (bf16 transposed weights)
    //            Wt0 region is DEAD after gemm<0> -> reused for Invs (512 KB)
    //   8 MB   : Qp        16 MB  bf16 [B,H,S,64]
    //   24 MB  : Kp        16 MB  bf16 [B,H,S,64]
    //   40 MB  : VpT       16 MB  bf16 [B,H,64,S]
    //   56 MB  : Ctx       32 MB  f32  [B,S,1024]
    ushort* Wt0 = (ushort*)ws;
    ushort* Wt1 = Wt0 + (size_t)1024 * 1024;
    ushort* Wt2 = Wt1 + (size_t)1024 * 1024;
    ushort* Wt3 = Wt2 + (size_t)1024 * 1024;
    ushort* Qp  = (ushort*)(ws + ((size_t)8  << 20));
    ushort* Kp  = (ushort*)(ws + ((size_t)24 << 20));
    ushort* VpT = (ushort*)(ws + ((size_t)40 << 20));
    float*  Ctx = (float*) (ws + ((size_t)56 << 20));
    float*  Invs = (float*)ws;                // overlays Wt0 (dead by attn_pv)

    float* outp = (float*)d_out;              // [B,S,D] final (pre-LN staged here)
    float* attn = outp + OUT_ELEMS;           // [B,H,S,S]

    transpose_w<<<dim3(16, 16, 4), 256, 0, stream>>>(Wq, Wk, Wv, Wfc, Wt0, Wt1, Wt2, Wt3);
    gemm_bt<0><<<dim3(512), 256, 0, stream>>>(Xq, Wt0, Qp);
    gemm_bt<0><<<dim3(512), 256, 0, stream>>>(Xk, Wt1, Kp);
    gemm_bt<1><<<dim3(512), 256, 0, stream>>>(Xv, Wt2, VpT);
    attn_pv<<<dim3(8, 16, 8), 256, 0, stream>>>(Qp, Kp, VpT, Invs, Ctx);
    attn_write<<<dim3(32, 16, 8), 256, 0, stream>>>(Qp, Kp, Invs, attn);
    gemm_bt<2><<<dim3(512), 256, 0, stream>>>(Ctx, Wt3, outp);
    ln_kernel<<<MM, 256, 0, stream>>>(Xq, outp);
}

// Round 2
// 990.807 us; speedup vs baseline: 1.2445x; 1.1683x over previous
//
#include <hip/hip_runtime.h>
#include <hip/hip_bf16.h>

// Problem constants
#define BB 8
#define SS 1024
#define DD 1024
#define HH 16
#define DKK 64
#define MM (BB*SS)          // 8192
#define OUT_ELEMS ((size_t)BB*SS*DD)          // 8388608
#define ATTN_ELEMS ((size_t)BB*HH*SS*SS)      // 134217728

using short8  = __attribute__((ext_vector_type(8))) short;
using ushort8 = __attribute__((ext_vector_type(8))) ushort;
using f32x4   = __attribute__((ext_vector_type(4))) float;

__device__ __forceinline__ ushort f2b(float f) {
    unsigned u = __float_as_uint(f);
    u = u + 0x7fffu + ((u >> 16) & 1u);
    return (ushort)(u >> 16);
}

// async 16B global->LDS (m97 pattern). LDS dest is wave-uniform base; HW adds lane*16.
__device__ __forceinline__ void glds16(const ushort* g, ushort* l) {
    __builtin_amdgcn_global_load_lds(
        (const __attribute__((address_space(1))) void*)g,
        (__attribute__((address_space(3))) void*)l, 16, 0, 0);
}

// ---------------------------------------------------------------------------
// Weight transpose + bf16 convert: Wt[n][k] = bf16(W[k][n]), 1024x1024 each.
// ---------------------------------------------------------------------------
__global__ __launch_bounds__(256) void transpose_w(
    const float* __restrict__ w0, const float* __restrict__ w1,
    const float* __restrict__ w2, const float* __restrict__ w3,
    ushort* __restrict__ t0, ushort* __restrict__ t1,
    ushort* __restrict__ t2, ushort* __restrict__ t3)
{
    const float* W; ushort* T;
    switch (blockIdx.z) {
        case 0: W = w0; T = t0; break;
        case 1: W = w1; T = t1; break;
        case 2: W = w2; T = t2; break;
        default: W = w3; T = t3; break;
    }
    __shared__ float tile[64 * 65];
    const int k0 = blockIdx.x * 64, n0 = blockIdx.y * 64;
    const int t = threadIdx.x;
#pragma unroll
    for (int i = 0; i < 16; i++) {
        int idx = i * 256 + t;
        int r = idx >> 6, c = idx & 63;
        tile[r * 65 + c] = W[(size_t)(k0 + r) * DD + n0 + c];
    }
    __syncthreads();
#pragma unroll
    for (int i = 0; i < 16; i++) {
        int idx = i * 256 + t;
        int nr = idx >> 6, kc = idx & 63;
        T[(size_t)(n0 + nr) * DD + k0 + kc] = f2b(tile[kc * 65 + nr]);
    }
}

// ---------------------------------------------------------------------------
// Streaming f32 -> bf16 convert (row-major, 8M elems). Bit-identical to the
// f2b the old GEMM applied during LDS staging, hoisted out once.
// ---------------------------------------------------------------------------
__global__ __launch_bounds__(256) void convert_bf16(
    const float* __restrict__ in, ushort* __restrict__ out)
{
    const size_t i = ((size_t)blockIdx.x * 256 + threadIdx.x) * 8;
    float4 a = *(const float4*)&in[i];
    float4 b = *(const float4*)&in[i + 4];
    ushort8 o;
    o[0] = f2b(a.x); o[1] = f2b(a.y); o[2] = f2b(a.z); o[3] = f2b(a.w);
    o[4] = f2b(b.x); o[5] = f2b(b.y); o[6] = f2b(b.z); o[7] = f2b(b.w);
    *(ushort8*)&out[i] = o;
}

// ---------------------------------------------------------------------------
// GEMM (m97 structure): C[8192][1024] = Ab[bf16 MxK row-major] * Wt^T
// (Wt is [N][K] bf16). 128x128 tile, BK=32, 4 waves x (64x64 via 4x4 frags of
// 16x16x32 MFMA). Both tiles staged with global_load_lds width 16 (linear LDS,
// no swizzle: T2 is null at 128^2 + 2-phase per regime gate). Chunked XCD
// swizzle (512 % 8 == 0) so each XCD owns 8 complete m-panels.
// MODE 0: bf16 out, head-major [B,H,S,64]
// MODE 1: bf16 out, V-transposed [B,H,64,S]
// MODE 2: f32 out, row-major [M][N]
// ---------------------------------------------------------------------------
template <int MODE>
__global__ __launch_bounds__(256) void gemm_a16(
    const ushort* __restrict__ Ab, const ushort* __restrict__ Bt,
    void* __restrict__ Cout)
{
    constexpr int K = 1024;
    const int t = threadIdx.x;
    const int wg = blockIdx.x;
    const int l  = (wg & 7) * 64 + (wg >> 3);
    const int n0 = (l & 7) * 128, m0 = (l >> 3) * 128;
    const int lane = t & 63, w = t >> 6;
    const int li = lane & 15, quad = lane >> 4;
    const int wm = w >> 1, wn = w & 1;

    __shared__ ushort As[128 * 32];   // [row][k] linear, row stride 64 B
    __shared__ ushort Bs[128 * 32];

    // staging: 8 KB per tile = 8 segments of 1024 B; wave w covers segs w, w+4.
    // lane lane in seg s -> row s*16 + lane/4, col (lane&3)*8 (16 B chunk).
    const int srow0 = w * 16 + (lane >> 2);
    const int srow1 = (w + 4) * 16 + (lane >> 2);
    const int scol  = (lane & 3) * 8;
    const ushort* gA0 = &Ab[(size_t)(m0 + srow0) * K + scol];
    const ushort* gA1 = &Ab[(size_t)(m0 + srow1) * K + scol];
    const ushort* gB0 = &Bt[(size_t)(n0 + srow0) * K + scol];
    const ushort* gB1 = &Bt[(size_t)(n0 + srow1) * K + scol];
    ushort* lA0 = &As[(size_t)w * 512];
    ushort* lA1 = &As[(size_t)(w + 4) * 512];
    ushort* lB0 = &Bs[(size_t)w * 512];
    ushort* lB1 = &Bs[(size_t)(w + 4) * 512];

    f32x4 acc[4][4];
    const f32x4 zf = {0.f, 0.f, 0.f, 0.f};
#pragma unroll
    for (int mf = 0; mf < 4; mf++)
#pragma unroll
        for (int nf = 0; nf < 4; nf++) acc[mf][nf] = zf;

    for (int kk = 0; kk < K; kk += 32) {
        __syncthreads();            // prior iter's ds_reads done before overwrite
        glds16(gA0 + kk, lA0);
        glds16(gA1 + kk, lA1);
        glds16(gB0 + kk, lB0);
        glds16(gB1 + kk, lB1);
        __syncthreads();            // compiler drains vmcnt(0) before s_barrier

        short8 af[4], bfr[4];
#pragma unroll
        for (int mf = 0; mf < 4; mf++)
            af[mf] = *(const short8*)&As[(wm * 64 + mf * 16 + li) * 32 + quad * 8];
#pragma unroll
        for (int nf = 0; nf < 4; nf++)
            bfr[nf] = *(const short8*)&Bs[(wn * 64 + nf * 16 + li) * 32 + quad * 8];
#pragma unroll
        for (int mf = 0; mf < 4; mf++)
#pragma unroll
            for (int nf = 0; nf < 4; nf++)
                acc[mf][nf] = __builtin_amdgcn_mfma_f32_16x16x32_bf16(af[mf], bfr[nf], acc[mf][nf], 0, 0, 0);
    }

#pragma unroll
    for (int mf = 0; mf < 4; mf++)
#pragma unroll
        for (int nf = 0; nf < 4; nf++)
#pragma unroll
            for (int r = 0; r < 4; r++) {
                int m = m0 + wm * 64 + mf * 16 + quad * 4 + r;
                int n = n0 + wn * 64 + nf * 16 + li;
                float v = acc[mf][nf][r];
                if (MODE == 0) {
                    int b = m >> 10, s = m & 1023, h = n >> 6, d = n & 63;
                    ((ushort*)Cout)[((size_t)(b * HH + h) * SS + s) * 64 + d] = f2b(v);
                } else if (MODE == 1) {
                    int b = m >> 10, s = m & 1023, h = n >> 6, d = n & 63;
                    ((ushort*)Cout)[((size_t)(b * HH + h) * 64 + d) * SS + s] = f2b(v);
                } else {
                    ((float*)Cout)[(size_t)m * 1024 + n] = v;
                }
            }
}

// ---------------------------------------------------------------------------
// Pass 1 of attention: per (b,h), row inverse-sums + normalized context
// (written directly as bf16 [B,S,H*64] = the fc GEMM's A matrix; identical
// rounding to the old f32->bf16 staging). Work-balanced q-tile pairs
// (pr, 15-pr) -> every block does exactly 34 key-chunks. Barrier-free P tile
// (per-wave LDS + compiler fence). Flattened grid + chunked XCD swizzle so
// each XCD owns 16 complete (b,h) panels (K/V fetched once per XCD).
// ---------------------------------------------------------------------------
__global__ __launch_bounds__(256) void attn_pv(
    const ushort* __restrict__ Qp, const ushort* __restrict__ Kp,
    const ushort* __restrict__ VpT, float* __restrict__ Invs,
    ushort* __restrict__ CtxB)
{
    const int wg = blockIdx.x;              // 0..1023
    const int lid = (wg & 7) * 128 + (wg >> 3);
    const int pr = lid & 7;                 // tile pair 0..7
    const int bh = lid >> 3;                // 0..127
    const int h = bh & 15, b = bh >> 4;
    const int t = threadIdx.x;
    const int w = t >> 6, lane = t & 63;
    const int li = lane & 15, quad = lane >> 4;

    const ushort* Qh = Qp  + (size_t)bh * SS * 64;
    const ushort* Kh = Kp  + (size_t)bh * SS * 64;
    const ushort* Vt = VpT + (size_t)bh * 64 * SS;

    __shared__ ushort Ps[4][16 * 32];   // per-wave P tile [16 q][32 keys]
    ushort* myP = Ps[w];
    const f32x4 zf = {0.f, 0.f, 0.f, 0.f};

    for (int sel = 0; sel < 2; sel++) {
        const int qt = sel ? (15 - pr) : pr;
        const int qbase = qt * 64 + w * 16;

        short8 aq0 = *(const short8*)&Qh[(size_t)(qbase + li) * 64 + quad * 8];
        short8 aq1 = *(const short8*)&Qh[(size_t)(qbase + li) * 64 + 32 + quad * 8];

        float lsum[4] = {0.f, 0.f, 0.f, 0.f};
        f32x4 cacc[4];
#pragma unroll
        for (int vf = 0; vf < 4; vf++) cacc[vf] = zf;

        const int nch = (qt + 1) * 2;

        for (int c = 0; c < nch; c++) {
            const int kb = c * 32;
#pragma unroll
            for (int half = 0; half < 2; half++) {
                const int col = kb + half * 16 + li;
                short8 bk0 = *(const short8*)&Kh[(size_t)col * 64 + quad * 8];
                short8 bk1 = *(const short8*)&Kh[(size_t)col * 64 + 32 + quad * 8];
                f32x4 s = __builtin_amdgcn_mfma_f32_16x16x32_bf16(aq0, bk0, zf, 0, 0, 0);
                s = __builtin_amdgcn_mfma_f32_16x16x32_bf16(aq1, bk1, s, 0, 0, 0);
#pragma unroll
                for (int r = 0; r < 4; r++) {
                    const int row = qbase + quad * 4 + r;
                    float p = (col <= row) ? __expf(s[r] * 0.125f) : 0.f;
                    lsum[r] += p;
                    myP[(quad * 4 + r) * 32 + half * 16 + li] = f2b(p);
                }
            }
            asm volatile("" ::: "memory");
            short8 ap = *(const short8*)&myP[li * 32 + quad * 8];
#pragma unroll
            for (int vf = 0; vf < 4; vf++) {
                short8 bv = *(const short8*)&Vt[(size_t)(vf * 16 + li) * SS + kb + quad * 8];
                cacc[vf] = __builtin_amdgcn_mfma_f32_16x16x32_bf16(ap, bv, cacc[vf], 0, 0, 0);
            }
            asm volatile("" ::: "memory");
        }

#pragma unroll
        for (int r = 0; r < 4; r++) {
            float v = lsum[r];
            v += __shfl_xor(v, 1, 64);
            v += __shfl_xor(v, 2, 64);
            v += __shfl_xor(v, 4, 64);
            v += __shfl_xor(v, 8, 64);
            lsum[r] = 1.f / v;
        }
        if (li == 0) {
#pragma unroll
            for (int r = 0; r < 4; r++)
                Invs[(size_t)bh * SS + qbase + quad * 4 + r] = lsum[r];
        }

        // Normalize + store context as bf16 (feeds gemm_a16<2> directly)
#pragma unroll
        for (int vf = 0; vf < 4; vf++)
#pragma unroll
            for (int r = 0; r < 4; r++) {
                const int s_idx = qbase + quad * 4 + r;
                CtxB[((size_t)b * SS + s_idx) * DD + h * 64 + vf * 16 + li] = f2b(cacc[vf][r] * lsum[r]);
            }
    }
}

// ---------------------------------------------------------------------------
// Pass 2: stream out the full attn matrix (536 MB f32). 4096 uniform blocks,
// chunked XCD swizzle so the 32 blocks of each (b,h) share one XCD's L2.
// Fully-masked 64-col chunks -> float4 zero fill; live chunks recompute
// scores via MFMA and scale by precomputed inverse sums.
// ---------------------------------------------------------------------------
__global__ __launch_bounds__(256) void attn_write(
    const ushort* __restrict__ Qp, const ushort* __restrict__ Kp,
    const float* __restrict__ Invs, float* __restrict__ attn)
{
    const int wg = blockIdx.x;              // 0..4095
    const int lid = (wg & 7) * 512 + (wg >> 3);
    const int bh = lid >> 5;                // 0..127
    const int qt = (lid & 31) >> 1;         // 0..15
    const int ch = lid & 1;                 // column half
    const int t = threadIdx.x;
    const int w = t >> 6, lane = t & 63;
    const int li = lane & 15, quad = lane >> 4;
    const int qbase = qt * 64 + w * 16;
    const int c0 = ch * 512;

    const ushort* Qh = Qp + (size_t)bh * SS * 64;
    const ushort* Kh = Kp + (size_t)bh * SS * 64;
    float* arow = attn + (size_t)bh * SS * SS;

    const f32x4 zf = {0.f, 0.f, 0.f, 0.f};

    short8 aq0 = *(const short8*)&Qh[(size_t)(qbase + li) * 64 + quad * 8];
    short8 aq1 = *(const short8*)&Qh[(size_t)(qbase + li) * 64 + 32 + quad * 8];
    float inv[4];
#pragma unroll
    for (int r = 0; r < 4; r++)
        inv[r] = Invs[(size_t)bh * SS + qbase + quad * 4 + r];

    for (int c64 = 0; c64 < 8; c64++) {
        const int kb = c0 + c64 * 64;
        if (kb > qbase + 15) {
#pragma unroll
            for (int r = 0; r < 4; r++) {
                const int row = qbase + quad * 4 + r;
                *(f32x4*)&arow[(size_t)row * SS + kb + li * 4] = zf;
            }
        } else {
#pragma unroll
            for (int q16 = 0; q16 < 4; q16++) {
                const int col = kb + q16 * 16 + li;
                short8 bk0 = *(const short8*)&Kh[(size_t)col * 64 + quad * 8];
                short8 bk1 = *(const short8*)&Kh[(size_t)col * 64 + 32 + quad * 8];
                f32x4 s = __builtin_amdgcn_mfma_f32_16x16x32_bf16(aq0, bk0, zf, 0, 0, 0);
                s = __builtin_amdgcn_mfma_f32_16x16x32_bf16(aq1, bk1, s, 0, 0, 0);
#pragma unroll
                for (int r = 0; r < 4; r++) {
                    const int row = qbase + quad * 4 + r;
                    float p = (col <= row) ? __expf(s[r] * 0.125f) * inv[r] : 0.f;
                    arow[(size_t)row * SS + col] = p;
                }
            }
        }
    }
}

// ---------------------------------------------------------------------------
// Residual add + LayerNorm (gamma=1,beta=0), in-place on pre-LN rows in d_out.
// ---------------------------------------------------------------------------
__global__ __launch_bounds__(256) void ln_kernel(
    const float* __restrict__ res, float* __restrict__ io)
{
    const int row = blockIdx.x;
    const int t = threadIdx.x;
    float4 p4 = *(const float4*)&io[(size_t)row * DD + t * 4];
    float4 r4 = *(const float4*)&res[(size_t)row * DD + t * 4];
    float x0 = p4.x + r4.x, x1 = p4.y + r4.y, x2 = p4.z + r4.z, x3 = p4.w + r4.w;
    float s  = x0 + x1 + x2 + x3;
    float ss = x0 * x0 + x1 * x1 + x2 * x2 + x3 * x3;
#pragma unroll
    for (int m = 1; m < 64; m <<= 1) {
        s  += __shfl_xor(s, m, 64);
        ss += __shfl_xor(ss, m, 64);
    }
    __shared__ float red[8];
    const int w = t >> 6, lane = t & 63;
    if (lane == 0) { red[w] = s; red[4 + w] = ss; }
    __syncthreads();
    if (t == 0) {
        float S1 = red[0] + red[1] + red[2] + red[3];
        float S2 = red[4] + red[5] + red[6] + red[7];
        float mu = S1 * (1.f / 1024.f);
        float var = S2 * (1.f / 1024.f) - mu * mu;
        red[0] = mu;
        red[1] = rsqrtf(var + 1e-5f);
    }
    __syncthreads();
    float mu = red[0], rs = red[1];
    float4 o;
    o.x = (x0 - mu) * rs; o.y = (x1 - mu) * rs;
    o.z = (x2 - mu) * rs; o.w = (x3 - mu) * rs;
    *(float4*)&io[(size_t)row * DD + t * 4] = o;
}

// ---------------------------------------------------------------------------
extern "C" void kernel_launch(void* const* d_in, const int* in_sizes, int n_in,
                              void* d_out, int out_size, void* d_ws, size_t ws_size,
                              hipStream_t stream)
{
    const float* Xq  = (const float*)d_in[0];
    const float* Xk  = (const float*)d_in[1];
    const float* Xv  = (const float*)d_in[2];
    // d_in[3] = attn_mask (causal) — computed analytically, unused
    const float* Wq  = (const float*)d_in[4];
    const float* Wk  = (const float*)d_in[5];
    const float* Wv  = (const float*)d_in[6];
    const float* Wfc = (const float*)d_in[7];

    char* ws = (char*)d_ws;
    // ws layout (72 MB used):
    //   0      : Wt0..Wt3   4 x 2 MB  (bf16 transposed weights)
    //            Wt0 region dead after gemm Q -> reused for Invs (512 KB)
    //   8 MB   : Qp   16 MB  bf16 [B,H,S,64]
    //   24 MB  : Kp   16 MB  bf16 [B,H,S,64]
    //   40 MB  : VpT  16 MB  bf16 [B,H,64,S]
    //   56 MB  : Xb   16 MB  bf16 [8192][1024] — time-shared: Xqb, Xkb, Xvb, CtxB
    ushort* Wt0 = (ushort*)ws;
    ushort* Wt1 = Wt0 + (size_t)1024 * 1024;
    ushort* Wt2 = Wt1 + (size_t)1024 * 1024;
    ushort* Wt3 = Wt2 + (size_t)1024 * 1024;
    ushort* Qp  = (ushort*)(ws + ((size_t)8  << 20));
    ushort* Kp  = (ushort*)(ws + ((size_t)24 << 20));
    ushort* VpT = (ushort*)(ws + ((size_t)40 << 20));
    ushort* Xb  = (ushort*)(ws + ((size_t)56 << 20));
    float*  Invs = (float*)ws;                // overlays Wt0 (dead by attn_pv)

    float* outp = (float*)d_out;              // [B,S,D] final (pre-LN staged here)
    float* attn = outp + OUT_ELEMS;           // [B,H,S,S]

    transpose_w<<<dim3(16, 16, 4), 256, 0, stream>>>(Wq, Wk, Wv, Wfc, Wt0, Wt1, Wt2, Wt3);
    convert_bf16<<<4096, 256, 0, stream>>>(Xq, Xb);
    gemm_a16<0><<<512, 256, 0, stream>>>(Xb, Wt0, Qp);
    convert_bf16<<<4096, 256, 0, stream>>>(Xk, Xb);
    gemm_a16<0><<<512, 256, 0, stream>>>(Xb, Wt1, Kp);
    convert_bf16<<<4096, 256, 0, stream>>>(Xv, Xb);
    gemm_a16<1><<<512, 256, 0, stream>>>(Xb, Wt2, VpT);
    attn_pv<<<1024, 256, 0, stream>>>(Qp, Kp, VpT, Invs, Xb);   // Xb now = CtxB
    attn_write<<<4096, 256, 0, stream>>>(Qp, Kp, Invs, attn);
    gemm_a16<2><<<512, 256, 0, stream>>>(Xb, Wt3, outp);
    ln_kernel<<<MM, 256, 0, stream>>>(Xq, outp);
}